// Round 12
// baseline (352.473 us; speedup 1.0000x reference)
//
#include <hip/hip_runtime.h>
#include <hip/hip_bf16.h>
#include <math.h>

// Problem constants
#define D_MODEL 768
#define D_FF    3072
#define N_HEAD  12
#define HEAD_D  64
#define BATCH   2
#define SEQ     2048
#define QKV_LD  2304

typedef __attribute__((ext_vector_type(8))) short short8;            // 8 bf16 (4 VGPRs)
typedef __attribute__((ext_vector_type(8))) unsigned short ushort8;  // 16B staging
typedef __attribute__((ext_vector_type(4))) float f32x4;             // MFMA C/D frag

__device__ inline unsigned short f2bf(float f) {
    union { __hip_bfloat16 b; unsigned short u; } cv;
    cv.b = __float2bfloat16(f);
    return cv.u;
}

__device__ inline float bf2f(unsigned short u) {
    union { unsigned int i; float f; } cv;
    cv.i = ((unsigned int)u) << 16;
    return cv.f;
}

__device__ inline void async_load16(const void* g, void* l) {
    __builtin_amdgcn_global_load_lds(
        (const __attribute__((address_space(1))) void*)g,
        (__attribute__((address_space(3))) void*)l, 16, 0, 0);
}

// ---------------- fused fp32->bf16 conversions + bias pack -------------------------
__global__ __launch_bounds__(256) void conv_fused(
    const float* __restrict__ x,
    const float* __restrict__ Wq, const float* __restrict__ Wk,
    const float* __restrict__ Wv, const float* __restrict__ Wp,
    const float* __restrict__ W1, const float* __restrict__ W2,
    const float* __restrict__ bq, const float* __restrict__ bk,
    const float* __restrict__ bv,
    unsigned short* __restrict__ xb, unsigned short* __restrict__ wqkvb,
    unsigned short* __restrict__ wpb, unsigned short* __restrict__ w1b,
    unsigned short* __restrict__ w2b, float* __restrict__ bqkv)
{
    int bid = blockIdx.x;
    const float* src; unsigned short* dst; int base;
    if      (bid < 3072) { src = x;  dst = xb;              base = bid;        }
    else if (bid < 3648) { src = Wq; dst = wqkvb;           base = bid - 3072; }
    else if (bid < 4224) { src = Wk; dst = wqkvb + 589824;  base = bid - 3648; }
    else if (bid < 4800) { src = Wv; dst = wqkvb + 1179648; base = bid - 4224; }
    else if (bid < 5376) { src = Wp; dst = wpb;             base = bid - 4800; }
    else if (bid < 7680) { src = W1; dst = w1b;             base = bid - 5376; }
    else if (bid < 9984) { src = W2; dst = w2b;             base = bid - 7680; }
    else {
        for (int j = threadIdx.x; j < QKV_LD; j += 256)
            bqkv[j] = (j < 768) ? bq[j] : (j < 1536) ? bk[j - 768] : bv[j - 1536];
        return;
    }
    int i = (base * 256 + threadIdx.x) * 4;
    float4 v = *(const float4*)(src + i);
    ushort4 o4;
    o4.x = f2bf(v.x); o4.y = f2bf(v.y); o4.z = f2bf(v.z); o4.w = f2bf(v.w);
    *(ushort4*)(dst + i) = o4;
}

// ---------------- bf16 MFMA GEMM: R1-EXACT monolithic 3-stage pipeline -------------
// Used only by proj now. Kept non-templated / branch-free (templates regressed).
// mode 0: outf=acc+bias   1: +bf16 res   2: bf16(gelu(acc+bias))   3: bf16(acc+bias)
#define NSTAGE 3

__global__ __launch_bounds__(256) void gemm_bf16(
    const unsigned short* __restrict__ A, int lda,
    const unsigned short* __restrict__ W, int ldw,
    const float* __restrict__ bias,
    const unsigned short* __restrict__ resb, int ldr,
    float* __restrict__ outf, unsigned short* __restrict__ outb,
    float* __restrict__ pacc, int ldo,
    int M, int N, int K, int mode)
{
    __shared__ unsigned short As[NSTAGE][128 * 32];   // 8 KB per stage
    __shared__ unsigned short Bs[NSTAGE][128 * 32];

    const int t    = threadIdx.x;
    const int lane = t & 63;
    const int wv   = t >> 6;
    const int wm   = wv >> 1;
    const int wn   = wv & 1;
    const int bm   = blockIdx.y * 128;
    const int bn   = blockIdx.x * 128;
    const int kz   = blockIdx.z;
    const int Kc   = K / gridDim.z;

    const int qd   = lane >> 4;
    const int l16  = lane & 15;

    f32x4 acc[4][4];
    #pragma unroll
    for (int i = 0; i < 4; i++)
        #pragma unroll
        for (int j = 0; j < 4; j++)
            acc[i][j] = (f32x4){0.f, 0.f, 0.f, 0.f};

    // staging: chunk c = wv*2+i covers LDS rows c*16..+15; lane l -> +l*16B
    const int srow = lane >> 2;
    const int sseg = (lane & 3) * 8;
    const int r0   = (wv * 2 + 0) * 16 + srow;
    const int r1   = (wv * 2 + 1) * 16 + srow;
    const size_t gA0 = (size_t)(bm + r0) * lda + sseg;
    const size_t gA1 = (size_t)(bm + r1) * lda + sseg;
    const size_t gB0 = (size_t)(bn + r0) * ldw + sseg;
    const size_t gB1 = (size_t)(bn + r1) * ldw + sseg;
    const int c0 = (wv * 2 + 0) * 512;
    const int c1 = (wv * 2 + 1) * 512;

    const int kbeg  = kz * Kc;
    const int niter = Kc / 32;

    // prologue: tiles 0,1
    async_load16(A + gA0 + kbeg, &As[0][c0]);
    async_load16(W + gB0 + kbeg, &Bs[0][c0]);
    async_load16(A + gA1 + kbeg, &As[0][c1]);
    async_load16(W + gB1 + kbeg, &Bs[0][c1]);
    if (niter > 1) {
        async_load16(A + gA0 + kbeg + 32, &As[1][c0]);
        async_load16(W + gB0 + kbeg + 32, &Bs[1][c0]);
        async_load16(A + gA1 + kbeg + 32, &As[1][c1]);
        async_load16(W + gB1 + kbeg + 32, &Bs[1][c1]);
    }

    int stage = 0;
    for (int it = 0; it < niter; it++) {
        if (it + 1 < niter) __builtin_amdgcn_s_waitcnt(0x0F74);  // vmcnt(4)
        else                __builtin_amdgcn_s_waitcnt(0x0F70);  // vmcnt(0)
        __builtin_amdgcn_s_barrier();   // tile it ready everywhere; stage (it-1)%3 free

        if (it + 2 < niter) {
            const int sn = (stage + 2 >= NSTAGE) ? stage + 2 - NSTAGE : stage + 2;
            const int kn = kbeg + (it + 2) * 32;
            async_load16(A + gA0 + kn, &As[sn][c0]);
            async_load16(W + gB0 + kn, &Bs[sn][c0]);
            async_load16(A + gA1 + kn, &As[sn][c1]);
            async_load16(W + gB1 + kn, &Bs[sn][c1]);
        }

        short8 af[4], bf[4];
        #pragma unroll
        for (int mt = 0; mt < 4; mt++)
            af[mt] = *(const short8*)(&As[stage][(wm * 64 + mt * 16 + l16) * 32 + qd * 8]);
        #pragma unroll
        for (int nt = 0; nt < 4; nt++)
            bf[nt] = *(const short8*)(&Bs[stage][(wn * 64 + nt * 16 + l16) * 32 + qd * 8]);
        #pragma unroll
        for (int mt = 0; mt < 4; mt++)
            #pragma unroll
            for (int nt = 0; nt < 4; nt++)
                acc[mt][nt] = __builtin_amdgcn_mfma_f32_16x16x32_bf16(
                    af[mt], bf[nt], acc[mt][nt], 0, 0, 0);

        stage = (stage == NSTAGE - 1) ? 0 : stage + 1;
    }

    #pragma unroll
    for (int mt = 0; mt < 4; mt++) {
        #pragma unroll
        for (int nt = 0; nt < 4; nt++) {
            int col = bn + wn * 64 + nt * 16 + l16;
            float bv = (kz == 0) ? bias[col] : 0.f;
            #pragma unroll
            for (int r = 0; r < 4; r++) {
                int row = bm + wm * 64 + mt * 16 + qd * 4 + r;
                if (kz != 0) {
                    pacc[(size_t)row * ldo + col] = acc[mt][nt][r];
                    continue;
                }
                float v = acc[mt][nt][r] + bv;
                if (mode == 1) {
                    v += bf2f(resb[(size_t)row * ldr + col]);
                    outf[(size_t)row * ldo + col] = v;
                } else if (mode == 2) {
                    v = 0.5f * v * (1.0f + erff(v * 0.70710678118654752f));
                    outb[(size_t)row * ldo + col] = f2bf(v);
                } else if (mode == 3) {
                    outb[(size_t)row * ldo + col] = f2bf(v);
                } else {
                    outf[(size_t)row * ldo + col] = v;
                }
            }
        }
    }
}

// ---------------- QKV GEMM v2: BK=64, NSTAGE=2, swizzled; 8x9 rect mapping ---------
// R11 proved the recipe on FFN2 (61 -> out of top-5, correctness held). QKV was
// 66us at 54 serial iters/CU (NS=4/BK=32); BK=64 halves to 27. Rect mapping kept
// byte-identical (FETCH-verified 18.1 MB). T2 both-sides swizzle as in FFN2 v2.
__global__ __launch_bounds__(256) void gemm_qkv(
    const unsigned short* __restrict__ A,
    const unsigned short* __restrict__ W,
    const float* __restrict__ bias,
    unsigned short* __restrict__ outb)
{
    __shared__ unsigned short As[2][128 * 64];   // 16 KB per stage
    __shared__ unsigned short Bs[2][128 * 64];

    const int t    = threadIdx.x;
    const int lane = t & 63;
    const int wv   = t >> 6;
    const int wm   = wv >> 1;
    const int wn   = wv & 1;

    // rect 8x9 per XCD over the 18x32 grid (assumes xcd = flat % 8 round-robin)
    const int flat = blockIdx.y * 18 + blockIdx.x;
    const int xcd  = flat & 7;
    const int u    = flat >> 3;
    const int mi   = (xcd >> 1) * 8 + u / 9;
    const int ni   = (xcd & 1) * 9 + u % 9;
    const int bm   = mi * 128;
    const int bn   = ni * 128;

    const int qd   = lane >> 4;
    const int l16  = lane & 15;

    f32x4 acc[4][4];
    #pragma unroll
    for (int i = 0; i < 4; i++)
        #pragma unroll
        for (int j = 0; j < 4; j++)
            acc[i][j] = (f32x4){0.f, 0.f, 0.f, 0.f};

    // staging: wave wv owns chunks wv*4+j (8 rows x 64 cols each); source col
    // pre-swizzled so phys slot p of row r holds logical slot p ^ (r&7).
    const int srow8 = lane >> 3;
    const int scol  = ((lane & 7) ^ srow8) * 8;
    const size_t gA_base = (size_t)(bm + wv * 32 + srow8) * D_MODEL + scol;
    const size_t gB_base = (size_t)(bn + wv * 32 + srow8) * D_MODEL + scol;
    const int ldsb = wv * 4 * 512;

    const int niter = D_MODEL / 64;   // 12

    // prologue: tile 0 -> stage 0
    #pragma unroll
    for (int j = 0; j < 4; j++) {
        async_load16(A + gA_base + (size_t)(j * 8) * D_MODEL, &As[0][ldsb + j * 512]);
        async_load16(W + gB_base + (size_t)(j * 8) * D_MODEL, &Bs[0][ldsb + j * 512]);
    }

    for (int it = 0; it < niter; it++) {
        __builtin_amdgcn_s_waitcnt(0x0F70);  // vmcnt(0)
        __builtin_amdgcn_s_barrier();
        const int st = it & 1;

        if (it + 1 < niter) {
            const int kn = (it + 1) * 64;
            #pragma unroll
            for (int j = 0; j < 4; j++) {
                async_load16(A + gA_base + (size_t)(j * 8) * D_MODEL + kn, &As[st ^ 1][ldsb + j * 512]);
                async_load16(W + gB_base + (size_t)(j * 8) * D_MODEL + kn, &Bs[st ^ 1][ldsb + j * 512]);
            }
        }

        #pragma unroll
        for (int kk = 0; kk < 2; kk++) {
            short8 af[4], bf[4];
            #pragma unroll
            for (int mt = 0; mt < 4; mt++) {
                const int row = wm * 64 + mt * 16 + l16;
                const int slot = (kk * 4 + qd) ^ (row & 7);
                af[mt] = *(const short8*)&As[st][row * 64 + slot * 8];
            }
            #pragma unroll
            for (int nt = 0; nt < 4; nt++) {
                const int row = wn * 64 + nt * 16 + l16;
                const int slot = (kk * 4 + qd) ^ (row & 7);
                bf[nt] = *(const short8*)&Bs[st][row * 64 + slot * 8];
            }
            #pragma unroll
            for (int mt = 0; mt < 4; mt++)
                #pragma unroll
                for (int nt = 0; nt < 4; nt++)
                    acc[mt][nt] = __builtin_amdgcn_mfma_f32_16x16x32_bf16(
                        af[mt], bf[nt], acc[mt][nt], 0, 0, 0);
        }
    }

    #pragma unroll
    for (int mt = 0; mt < 4; mt++) {
        #pragma unroll
        for (int nt = 0; nt < 4; nt++) {
            int col = bn + wn * 64 + nt * 16 + l16;
            float bv = bias[col];
            #pragma unroll
            for (int r = 0; r < 4; r++) {
                int row = bm + wm * 64 + mt * 16 + qd * 4 + r;
                outb[(size_t)row * QKV_LD + col] = f2bf(acc[mt][nt][r] + bv);
            }
        }
    }
}

// ---------------- FFN1 GEMM v2: BK=64, NSTAGE=2, swizzled; 8x12 rect + gelu --------
// Same proven recipe; mapping kept byte-identical (FETCH-verified 15.8 MB).
__global__ __launch_bounds__(256) void gemm_ffn1(
    const unsigned short* __restrict__ A,
    const unsigned short* __restrict__ W,
    const float* __restrict__ bias,
    unsigned short* __restrict__ outb)
{
    __shared__ unsigned short As[2][128 * 64];
    __shared__ unsigned short Bs[2][128 * 64];

    const int t    = threadIdx.x;
    const int lane = t & 63;
    const int wv   = t >> 6;
    const int wm   = wv >> 1;
    const int wn   = wv & 1;

    // rect 8x12 per XCD over the 24x32 grid (xcd = flat % 8 round-robin)
    const int flat = blockIdx.y * 24 + blockIdx.x;
    const int xcd  = flat & 7;
    const int u    = flat >> 3;
    const int mi   = (xcd >> 1) * 8 + u / 12;
    const int ni   = (xcd & 1) * 12 + u % 12;
    const int bm   = mi * 128;
    const int bn   = ni * 128;

    const int qd   = lane >> 4;
    const int l16  = lane & 15;

    f32x4 acc[4][4];
    #pragma unroll
    for (int i = 0; i < 4; i++)
        #pragma unroll
        for (int j = 0; j < 4; j++)
            acc[i][j] = (f32x4){0.f, 0.f, 0.f, 0.f};

    const int srow8 = lane >> 3;
    const int scol  = ((lane & 7) ^ srow8) * 8;
    const size_t gA_base = (size_t)(bm + wv * 32 + srow8) * D_MODEL + scol;
    const size_t gB_base = (size_t)(bn + wv * 32 + srow8) * D_MODEL + scol;
    const int ldsb = wv * 4 * 512;

    const int niter = D_MODEL / 64;   // 12

    #pragma unroll
    for (int j = 0; j < 4; j++) {
        async_load16(A + gA_base + (size_t)(j * 8) * D_MODEL, &As[0][ldsb + j * 512]);
        async_load16(W + gB_base + (size_t)(j * 8) * D_MODEL, &Bs[0][ldsb + j * 512]);
    }

    for (int it = 0; it < niter; it++) {
        __builtin_amdgcn_s_waitcnt(0x0F70);  // vmcnt(0)
        __builtin_amdgcn_s_barrier();
        const int st = it & 1;

        if (it + 1 < niter) {
            const int kn = (it + 1) * 64;
            #pragma unroll
            for (int j = 0; j < 4; j++) {
                async_load16(A + gA_base + (size_t)(j * 8) * D_MODEL + kn, &As[st ^ 1][ldsb + j * 512]);
                async_load16(W + gB_base + (size_t)(j * 8) * D_MODEL + kn, &Bs[st ^ 1][ldsb + j * 512]);
            }
        }

        #pragma unroll
        for (int kk = 0; kk < 2; kk++) {
            short8 af[4], bf[4];
            #pragma unroll
            for (int mt = 0; mt < 4; mt++) {
                const int row = wm * 64 + mt * 16 + l16;
                const int slot = (kk * 4 + qd) ^ (row & 7);
                af[mt] = *(const short8*)&As[st][row * 64 + slot * 8];
            }
            #pragma unroll
            for (int nt = 0; nt < 4; nt++) {
                const int row = wn * 64 + nt * 16 + l16;
                const int slot = (kk * 4 + qd) ^ (row & 7);
                bf[nt] = *(const short8*)&Bs[st][row * 64 + slot * 8];
            }
            #pragma unroll
            for (int mt = 0; mt < 4; mt++)
                #pragma unroll
                for (int nt = 0; nt < 4; nt++)
                    acc[mt][nt] = __builtin_amdgcn_mfma_f32_16x16x32_bf16(
                        af[mt], bf[nt], acc[mt][nt], 0, 0, 0);
        }
    }

    #pragma unroll
    for (int mt = 0; mt < 4; mt++) {
        #pragma unroll
        for (int nt = 0; nt < 4; nt++) {
            int col = bn + wn * 64 + nt * 16 + l16;
            float bv = bias[col];
            #pragma unroll
            for (int r = 0; r < 4; r++) {
                int row = bm + wm * 64 + mt * 16 + qd * 4 + r;
                float v = acc[mt][nt][r] + bv;
                v = 0.5f * v * (1.0f + erff(v * 0.70710678118654752f));
                outb[(size_t)row * D_FF + col] = f2bf(v);
            }
        }
    }
}

// ---------------- FFN2 GEMM v2: BK=64, NSTAGE=2, XOR-swizzled LDS (verified R11) ---
__global__ __launch_bounds__(256) void gemm_ffn2(
    const unsigned short* __restrict__ A,     // ff1b [4096,3072]
    const unsigned short* __restrict__ W,     // w2b  [768,3072]
    const float* __restrict__ bias,
    const unsigned short* __restrict__ resb,  // x1b
    float* __restrict__ outf,                 // y0
    float* __restrict__ pacc)                 // p1
{
    __shared__ unsigned short As[2][128 * 64];   // 16 KB per stage
    __shared__ unsigned short Bs[2][128 * 64];

    const int t    = threadIdx.x;
    const int lane = t & 63;
    const int wv   = t >> 6;
    const int wm   = wv >> 1;
    const int wn   = wv & 1;

    const int flat = blockIdx.x;          // 0..383
    const int g    = flat & 7;            // XCD
    const int u    = flat >> 3;           // 0..47
    const int kz   = g >> 2;              // K-half
    const int g2   = g & 3;               // row-stripe group
    const int band = u / 24;              // 2 bands of 4 rows (time-phased)
    const int rr   = (u % 24) / 6;
    const int cc   = u % 6;
    const int bm   = (g2 * 8 + band * 4 + rr) * 128;
    const int bn   = cc * 128;

    const int qd   = lane >> 4;
    const int l16  = lane & 15;

    f32x4 acc[4][4];
    #pragma unroll
    for (int i = 0; i < 4; i++)
        #pragma unroll
        for (int j = 0; j < 4; j++)
            acc[i][j] = (f32x4){0.f, 0.f, 0.f, 0.f};

    const int srow8 = lane >> 3;                    // 0..7 (row & 7)
    const int scol  = ((lane & 7) ^ srow8) * 8;     // swizzled source col (ushorts)
    const size_t gA_base = (size_t)(bm + wv * 32 + srow8) * D_FF + scol;
    const size_t gB_base = (size_t)(bn + wv * 32 + srow8) * D_FF + scol;
    const int ldsb = wv * 4 * 512;                  // element offset of chunk wv*4

    const int kbeg  = kz * (D_FF / 2);    // 0 or 1536
    const int niter = (D_FF / 2) / 64;    // 24

    #pragma unroll
    for (int j = 0; j < 4; j++) {
        async_load16(A + gA_base + (size_t)(j * 8) * D_FF + kbeg, &As[0][ldsb + j * 512]);
        async_load16(W + gB_base + (size_t)(j * 8) * D_FF + kbeg, &Bs[0][ldsb + j * 512]);
    }

    for (int it = 0; it < niter; it++) {
        __builtin_amdgcn_s_waitcnt(0x0F70);  // vmcnt(0): tile it landed
        __builtin_amdgcn_s_barrier();
        const int st = it & 1;

        if (it + 1 < niter) {
            const int kn = kbeg + (it + 1) * 64;
            #pragma unroll
            for (int j = 0; j < 4; j++) {
                async_load16(A + gA_base + (size_t)(j * 8) * D_FF + kn, &As[st ^ 1][ldsb + j * 512]);
                async_load16(W + gB_base + (size_t)(j * 8) * D_FF + kn, &Bs[st ^ 1][ldsb + j * 512]);
            }
        }

        #pragma unroll
        for (int kk = 0; kk < 2; kk++) {
            short8 af[4], bf[4];
            #pragma unroll
            for (int mt = 0; mt < 4; mt++) {
                const int row = wm * 64 + mt * 16 + l16;
                const int slot = (kk * 4 + qd) ^ (row & 7);
                af[mt] = *(const short8*)&As[st][row * 64 + slot * 8];
            }
            #pragma unroll
            for (int nt = 0; nt < 4; nt++) {
                const int row = wn * 64 + nt * 16 + l16;
                const int slot = (kk * 4 + qd) ^ (row & 7);
                bf[nt] = *(const short8*)&Bs[st][row * 64 + slot * 8];
            }
            #pragma unroll
            for (int mt = 0; mt < 4; mt++)
                #pragma unroll
                for (int nt = 0; nt < 4; nt++)
                    acc[mt][nt] = __builtin_amdgcn_mfma_f32_16x16x32_bf16(
                        af[mt], bf[nt], acc[mt][nt], 0, 0, 0);
        }
    }

    #pragma unroll
    for (int mt = 0; mt < 4; mt++) {
        #pragma unroll
        for (int nt = 0; nt < 4; nt++) {
            int col = bn + wn * 64 + nt * 16 + l16;
            #pragma unroll
            for (int r = 0; r < 4; r++) {
                int row = bm + wm * 64 + mt * 16 + qd * 4 + r;
                if (kz != 0) {
                    pacc[(size_t)row * D_MODEL + col] = acc[mt][nt][r];
                } else {
                    float v = acc[mt][nt][r] + bias[col]
                            + bf2f(resb[(size_t)row * D_MODEL + col]);
                    outf[(size_t)row * D_MODEL + col] = v;
                }
            }
        }
    }
}

// ---------------- one-shot V transpose: qkv V-part -> vT[b,h,d,s] ------------------
__global__ __launch_bounds__(256) void vtrans(
    const unsigned short* __restrict__ qkv, unsigned short* __restrict__ vT)
{
    __shared__ unsigned short T[64 * 72];
    const int t   = threadIdx.x;
    const int kt  = blockIdx.x;          // key tile
    const int bh  = blockIdx.y;
    const int h   = bh % N_HEAD;
    const int b   = bh / N_HEAD;
    const int row = t >> 2;              // token within tile
    const int c0  = (t & 3) * 16;        // dim start

    const unsigned short* src =
        qkv + (size_t)(b * SEQ + kt * 64 + row) * QKV_LD + 1536 + h * HEAD_D + c0;
    *(ushort8*)&T[row * 72 + c0]     = *(const ushort8*)src;
    *(ushort8*)&T[row * 72 + c0 + 8] = *(const ushort8*)(src + 8);
    __syncthreads();

    const int d = t >> 2;                // dim row to write
    ushort8 o0, o1;
    #pragma unroll
    for (int j = 0; j < 8; j++) o0[j] = T[(c0 + j) * 72 + d];
    #pragma unroll
    for (int j = 0; j < 8; j++) o1[j] = T[(c0 + 8 + j) * 72 + d];
    unsigned short* dst = vT + ((size_t)bh * HEAD_D + d) * SEQ + kt * 64 + c0;
    *(ushort8*)dst       = o0;
    *(ushort8*)(dst + 8) = o1;
}

// ---------------- MFMA flash attention: S^T form, KVBLK=128 ------------------------
// Verified R9-R11: 61-62.6 us. Do not modify without A/B.
#define ASTR 72
#define VSTR 136

__global__ __launch_bounds__(256) void attn_mfma(
    const unsigned short* __restrict__ qkv, const unsigned short* __restrict__ vT,
    const float* __restrict__ mask, unsigned short* __restrict__ out)
{
    __shared__ __align__(16) unsigned short Ks[128 * ASTR];
    __shared__ __align__(16) unsigned short Vt[64 * VSTR];
    __shared__ float Ms[128];

    const int t    = threadIdx.x;
    const int lane = t & 63;
    const int wv   = t >> 6;
    const int l16  = lane & 15;
    const int quad = lane >> 4;
    const int q0   = blockIdx.x * 64;
    const int bh   = blockIdx.y;
    const int h    = bh % N_HEAD;
    const int b    = bh / N_HEAD;
    const int NT   = SEQ / 128;   // 16

    const unsigned short* qb  = qkv + (size_t)b * SEQ * QKV_LD + h * HEAD_D;
    const unsigned short* kb  = qb + 768;
    const unsigned short* vtb = vT + (size_t)bh * HEAD_D * SEQ;

    // ---- stage Q tile (rows 0..63 of Ks, natural rows), pull Q B-frags ----
    {
        const int qsrow = t >> 2;
        const int qsc0  = (t & 3) * 16;
        const ushort8* src = (const ushort8*)(qb + (size_t)(q0 + qsrow) * QKV_LD + qsc0);
        *(ushort8*)&Ks[qsrow * ASTR + qsc0]     = src[0];
        *(ushort8*)&Ks[qsrow * ASTR + qsc0 + 8] = src[1];
    }
    __syncthreads();
    short8 bq0 = *(const short8*)&Ks[(wv * 16 + l16) * ASTR + quad * 8];
    short8 bq1 = *(const short8*)&Ks[(wv * 16 + l16) * ASTR + 32 + quad * 8];
    __syncthreads();

    // K staging: row = t>>1 (0..127 keys), dim start (t&1)*32 (64B = 4 ushort8)
    const int krow_s = t >> 1;
    const int kc0    = (t & 1) * 32;
    const int ks6    = krow_s & 63;
    const int ksig   = (krow_s & 64) |
                       ((ks6 & 0x23) | ((ks6 & 0x04) << 2) | ((ks6 & 0x18) >> 1));
    // V staging: dim row = t>>2 (0..63), key col start (t&3)*32
    const int vrow_s = t >> 2;
    const int vc0    = (t & 3) * 32;

    f32x4 o[4];
    #pragma unroll
    for (int i = 0; i < 4; i++) o[i] = (f32x4){0.f, 0.f, 0.f, 0.f};
    float m_st = -INFINITY, l_st = 0.f;

    // prefetch tile 0 into registers
    ushort8 rk0, rk1, rk2, rk3, rv0, rv1, rv2, rv3;
    float rm = 1.0f;
    {
        const ushort8* ksrc = (const ushort8*)(kb + (size_t)krow_s * QKV_LD + kc0);
        rk0 = ksrc[0]; rk1 = ksrc[1]; rk2 = ksrc[2]; rk3 = ksrc[3];
        const ushort8* vsrc = (const ushort8*)(vtb + (size_t)vrow_s * SEQ + vc0);
        rv0 = vsrc[0]; rv1 = vsrc[1]; rv2 = vsrc[2]; rv3 = vsrc[3];
        if (t < 128) rm = mask[b * SEQ + t];
    }

    for (int kt = 0; kt < NT; kt++) {
        // ---- store prefetched 128-key tile into LDS ----
        *(ushort8*)&Ks[ksig * ASTR + kc0]      = rk0;
        *(ushort8*)&Ks[ksig * ASTR + kc0 + 8]  = rk1;
        *(ushort8*)&Ks[ksig * ASTR + kc0 + 16] = rk2;
        *(ushort8*)&Ks[ksig * ASTR + kc0 + 24] = rk3;
        *(ushort8*)&Vt[vrow_s * VSTR + vc0]      = rv0;
        *(ushort8*)&Vt[vrow_s * VSTR + vc0 + 8]  = rv1;
        *(ushort8*)&Vt[vrow_s * VSTR + vc0 + 16] = rv2;
        *(ushort8*)&Vt[vrow_s * VSTR + vc0 + 24] = rv3;
        if (t < 128) Ms[t] = -10000.0f * (1.0f - rm);
        __syncthreads();

        // ---- prefetch next tile (latency hidden under compute) ----
        if (kt + 1 < NT) {
            const int kn = (kt + 1) * 128;
            const ushort8* ksrc = (const ushort8*)(kb + (size_t)(kn + krow_s) * QKV_LD + kc0);
            rk0 = ksrc[0]; rk1 = ksrc[1]; rk2 = ksrc[2]; rk3 = ksrc[3];
            const ushort8* vsrc = (const ushort8*)(vtb + (size_t)vrow_s * SEQ + kn + vc0);
            rv0 = vsrc[0]; rv1 = vsrc[1]; rv2 = vsrc[2]; rv3 = vsrc[3];
            if (t < 128) rm = mask[b * SEQ + kn + t];
        }

        // ---- S^T = K·Q^T over 8 slot-blocks, fused with mask+max ----
        float p[8][4];
        float mx = -3.0e38f;
        #pragma unroll
        for (int bi = 0; bi < 8; bi++) {
            const int krow = (bi * 16 + l16) * ASTR;
            short8 k0 = *(const short8*)&Ks[krow + quad * 8];
            short8 k1 = *(const short8*)&Ks[krow + 32 + quad * 8];
            f32x4 z = (f32x4){0.f, 0.f, 0.f, 0.f};
            z = __builtin_amdgcn_mfma_f32_16x16x32_bf16(k0, bq0, z, 0, 0, 0);
            z = __builtin_amdgcn_mfma_f32_16x16x32_bf16(k1, bq1, z, 0, 0, 0);
            const float4 m4 = *(const float4*)
                &Ms[(bi >> 2) * 64 + ((bi >> 1) & 1) * 32 + quad * 8 + (bi & 1) * 4];
            #pragma unroll
            for (int r = 0; r < 4; r++) {
                float s = fmaf(z[r], 0.125f, ((const float*)&m4)[r]);
                p[bi][r] = s;
                mx = fmaxf(mx, s);
            }
        }
        mx = fmaxf(mx, __shfl_xor(mx, 16, 64));
        mx = fmaxf(mx, __shfl_xor(mx, 32, 64));
        float m_new = fmaxf(m_st, mx);
        float alpha = __expf(m_st - m_new);
        m_st = m_new;
        float ls = 0.f;
        #pragma unroll
        for (int bi = 0; bi < 8; bi++) {
            #pragma unroll
            for (int r = 0; r < 4; r++) {
                p[bi][r] = __expf(p[bi][r] - m_new);
                ls += p[bi][r];
            }
        }
        ls += __shfl_xor(ls, 16, 64);
        ls += __shfl_xor(ls, 32, 64);
        l_st = l_st * alpha + ls;

        float ar[4];
        #pragma unroll
        for (int r = 0; r < 4; r++) ar[r] = __shfl(alpha, quad * 4 + r, 64);
        #pragma unroll
        for (int nt = 0; nt < 4; nt++)
            #pragma unroll
            for (int r = 0; r < 4; r++)
                o[nt][r] *= ar[r];

        // ---- pack P to bf16 A-frags: window w covers keys w*32..+31 ----
        short8 pf[4];
        #pragma unroll
        for (int w = 0; w < 4; w++) {
            #pragma unroll
            for (int bsel = 0; bsel < 2; bsel++) {
                #pragma unroll
                for (int r = 0; r < 4; r++)
                    pf[w][bsel * 4 + r] = (short)f2bf(p[w * 2 + bsel][r]);
            }
        }

        // ---- PV: O += P · V over 4 key-windows ----
        #pragma unroll
        for (int nt = 0; nt < 4; nt++) {
            const int vrow = (nt * 16 + l16) * VSTR;
            #pragma unroll
            for (int w = 0; w < 4; w++) {
                short8 vv = *(const short8*)&Vt[vrow + w * 32 + quad * 8];
                o[nt] = __builtin_amdgcn_mfma_f32_16x16x32_bf16(pf[w], vv, o[nt], 0, 0, 0);
            }
        }
        __syncthreads();
    }

    float inv = 1.0f / l_st;
    float ir[4];
    #pragma unroll
    for (int r = 0; r < 4; r++) ir[r] = __shfl(inv, quad * 4 + r, 64);
    #pragma unroll
    for (int nt = 0; nt < 4; nt++) {
        #pragma unroll
        for (int r = 0; r < 4; r++) {
            int qi = q0 + wv * 16 + quad * 4 + r;
            out[(size_t)(b * SEQ + qi) * D_MODEL + h * HEAD_D + nt * 16 + l16] =
                f2bf(o[nt][r] * ir[r]);
        }
    }
}

// ---------------- LayerNorm over 768; optional second f32 input (split-K partial) --
__global__ __launch_bounds__(256) void ln_kernel(
    const float* __restrict__ in, const float* __restrict__ in2,
    const float* __restrict__ g, const float* __restrict__ be,
    float* __restrict__ outf, unsigned short* __restrict__ outb)
{
    const int row = blockIdx.x;
    const int t   = threadIdx.x;
    const float* rp  = in  + (size_t)row * D_MODEL;
    const float* rp2 = in2 ? in2 + (size_t)row * D_MODEL : nullptr;

    float vals[3];
    float s = 0.f, s2 = 0.f;
    #pragma unroll
    for (int i = 0; i < 3; i++) {
        float x = rp[t + i * 256];
        if (rp2) x += rp2[t + i * 256];
        vals[i] = x;
        s += x; s2 += x * x;
    }
    #pragma unroll
    for (int off = 32; off >= 1; off >>= 1) {
        s  += __shfl_xor(s,  off, 64);
        s2 += __shfl_xor(s2, off, 64);
    }
    __shared__ float rs[4], rs2[4];
    __shared__ float mu_s, rstd_s;
    const int wave = t >> 6, lane = t & 63;
    if (lane == 0) { rs[wave] = s; rs2[wave] = s2; }
    __syncthreads();
    if (t == 0) {
        float S1 = rs[0] + rs[1] + rs[2] + rs[3];
        float S2 = rs2[0] + rs2[1] + rs2[2] + rs2[3];
        float mu  = S1 * (1.0f / D_MODEL);
        float var = S2 * (1.0f / D_MODEL) - mu * mu;
        mu_s = mu;
        rstd_s = rsqrtf(var + 1e-12f);
    }
    __syncthreads();
    const float mu = mu_s, rstd = rstd_s;
    #pragma unroll
    for (int i = 0; i < 3; i++) {
        int c = t + i * 256;
        float o = g[c] * (vals[i] - mu) * rstd + be[c];
        if (outf) outf[(size_t)row * D_MODEL + c] = o;
        if (outb) outb[(size_t)row * D_MODEL + c] = f2bf(o);
    }
}

extern "C" void kernel_launch(void* const* d_in, const int* in_sizes, int n_in,
                              void* d_out, int out_size, void* d_ws, size_t ws_size,
                              hipStream_t stream)
{
    const float* x    = (const float*)d_in[0];
    const float* mask = (const float*)d_in[1];
    const float* Wq   = (const float*)d_in[2];
    const float* bq   = (const float*)d_in[3];
    const float* Wk   = (const float*)d_in[4];
    const float* bk   = (const float*)d_in[5];
    const float* Wv   = (const float*)d_in[6];
    const float* bv   = (const float*)d_in[7];
    const float* Wp   = (const float*)d_in[8];
    const float* bp   = (const float*)d_in[9];
    const float* g1   = (const float*)d_in[10];
    const float* be1  = (const float*)d_in[11];
    const float* W1   = (const float*)d_in[12];
    const float* bf1  = (const float*)d_in[13];
    const float* W2   = (const float*)d_in[14];
    const float* bf2  = (const float*)d_in[15];
    const float* g2   = (const float*)d_in[16];
    const float* be2  = (const float*)d_in[17];

    const int M = BATCH * SEQ;   // 4096

    // ---- workspace layout (bytes), ~83.4 MB total ----
    char* ws = (char*)d_ws;
    unsigned short* qkvb  = (unsigned short*)(ws + 0);         // [4096,2304] bf16
    unsigned short* ff1b  = (unsigned short*)(ws + 0);         // [4096,3072] bf16 (qkvb dead)
    unsigned short* xb    = (unsigned short*)(ws + 25165824);  // [4096,768] bf16 (live thru proj)
    unsigned short* hb    = (unsigned short*)(ws + 31457280);  // [4096,768] bf16
    unsigned short* x1b   = (unsigned short*)(ws + 31457280);  // alias (hb dead after proj)
    float*          y0    = (float*)(ws + 37748736);           // [4096,768] f32
    unsigned short* wqkvb = (unsigned short*)(ws + 50331648);  // [2304,768]
    unsigned short* wpb   = (unsigned short*)(ws + 53870592);  // [768,768]
    unsigned short* w1b   = (unsigned short*)(ws + 55050240);  // [3072,768]
    unsigned short* w2b   = (unsigned short*)(ws + 59768832);  // [768,3072]
    float*          bqkv  = (float*)(ws + 64487424);           // [2304]
    float*          p1    = (float*)(ws + 64496640);           // [4096,768] f32 split-K partial
    unsigned short* vTb   = (unsigned short*)(ws + 77079552);  // [24,64,2048] bf16 (6.3MB)

    dim3 blk(256);

    conv_fused<<<dim3(9985), blk, 0, stream>>>(
        x, Wq, Wk, Wv, Wp, W1, W2, bq, bk, bv,
        xb, wqkvb, wpb, w1b, w2b, bqkv);

    // fused QKV GEMM -> bf16 (v2: BK=64/NS=2/swizzled; rect mapping kept)
    gemm_qkv<<<dim3(QKV_LD / 128, M / 128), blk, 0, stream>>>(xb, wqkvb, bqkv, qkvb);

    // one-shot V transpose
    vtrans<<<dim3(SEQ / 64, BATCH * N_HEAD), blk, 0, stream>>>(qkvb, vTb);

    // flash attention -> hb (bf16): KVBLK=128 (verified 61-62.6us)
    attn_mfma<<<dim3(SEQ / 64, BATCH * N_HEAD), blk, 0, stream>>>(qkvb, vTb, mask, hb);

    // proj + residual, split-K x2: y0 (z=0: bias + xb) + p1 (z=1 raw)
    gemm_bf16<<<dim3(D_MODEL / 128, M / 128, 2), blk, 0, stream>>>(
        hb, D_MODEL, wpb, D_MODEL, bp, xb, D_MODEL,
        y0, nullptr, p1, D_MODEL, M, D_MODEL, D_MODEL, 1);

    // LN1 over (y0 + p1) -> x1b (bf16)
    ln_kernel<<<dim3(M), blk, 0, stream>>>(y0, p1, g1, be1, nullptr, x1b);

    // FFN1 + gelu -> ff1b (v2: BK=64/NS=2/swizzled; rect mapping kept)
    gemm_ffn1<<<dim3(D_FF / 128, M / 128), blk, 0, stream>>>(x1b, w1b, bf1, ff1b);

    // FFN2 + residual, split-K x2 (v2 verified R11)
    gemm_ffn2<<<dim3(384), blk, 0, stream>>>(ff1b, w2b, bf2, x1b, y0, p1);

    // LN2 over (y0 + p1) -> out (f32)
    ln_kernel<<<dim3(M), blk, 0, stream>>>(y0, p1, g2, be2, (float*)d_out, nullptr);
}

// Round 13
// 333.080 us; speedup vs baseline: 1.0582x; 1.0582x over previous
//
#include <hip/hip_runtime.h>
#include <hip/hip_bf16.h>
#include <math.h>

// Problem constants
#define D_MODEL 768
#define D_FF    3072
#define N_HEAD  12
#define HEAD_D  64
#define BATCH   2
#define SEQ     2048
#define QKV_LD  2304

typedef __attribute__((ext_vector_type(8))) short short8;            // 8 bf16 (4 VGPRs)
typedef __attribute__((ext_vector_type(8))) unsigned short ushort8;  // 16B staging
typedef __attribute__((ext_vector_type(4))) float f32x4;             // MFMA C/D frag

__device__ inline unsigned short f2bf(float f) {
    union { __hip_bfloat16 b; unsigned short u; } cv;
    cv.b = __float2bfloat16(f);
    return cv.u;
}

__device__ inline float bf2f(unsigned short u) {
    union { unsigned int i; float f; } cv;
    cv.i = ((unsigned int)u) << 16;
    return cv.f;
}

__device__ inline void async_load16(const void* g, void* l) {
    __builtin_amdgcn_global_load_lds(
        (const __attribute__((address_space(1))) void*)g,
        (__attribute__((address_space(3))) void*)l, 16, 0, 0);
}

// ---------------- fused fp32->bf16 conversions + bias pack -------------------------
__global__ __launch_bounds__(256) void conv_fused(
    const float* __restrict__ x,
    const float* __restrict__ Wq, const float* __restrict__ Wk,
    const float* __restrict__ Wv, const float* __restrict__ Wp,
    const float* __restrict__ W1, const float* __restrict__ W2,
    const float* __restrict__ bq, const float* __restrict__ bk,
    const float* __restrict__ bv,
    unsigned short* __restrict__ xb, unsigned short* __restrict__ wqkvb,
    unsigned short* __restrict__ wpb, unsigned short* __restrict__ w1b,
    unsigned short* __restrict__ w2b, float* __restrict__ bqkv)
{
    int bid = blockIdx.x;
    const float* src; unsigned short* dst; int base;
    if      (bid < 3072) { src = x;  dst = xb;              base = bid;        }
    else if (bid < 3648) { src = Wq; dst = wqkvb;           base = bid - 3072; }
    else if (bid < 4224) { src = Wk; dst = wqkvb + 589824;  base = bid - 3648; }
    else if (bid < 4800) { src = Wv; dst = wqkvb + 1179648; base = bid - 4224; }
    else if (bid < 5376) { src = Wp; dst = wpb;             base = bid - 4800; }
    else if (bid < 7680) { src = W1; dst = w1b;             base = bid - 5376; }
    else if (bid < 9984) { src = W2; dst = w2b;             base = bid - 7680; }
    else {
        for (int j = threadIdx.x; j < QKV_LD; j += 256)
            bqkv[j] = (j < 768) ? bq[j] : (j < 1536) ? bk[j - 768] : bv[j - 1536];
        return;
    }
    int i = (base * 256 + threadIdx.x) * 4;
    float4 v = *(const float4*)(src + i);
    ushort4 o4;
    o4.x = f2bf(v.x); o4.y = f2bf(v.y); o4.z = f2bf(v.z); o4.w = f2bf(v.w);
    *(ushort4*)(dst + i) = o4;
}

// ---------------- bf16 MFMA GEMM: R1-EXACT monolithic 3-stage pipeline -------------
// Used only by proj. Kept non-templated / branch-free (templates regressed).
// mode 0: outf=acc+bias   1: +bf16 res   2: bf16(gelu(acc+bias))   3: bf16(acc+bias)
#define NSTAGE 3

__global__ __launch_bounds__(256) void gemm_bf16(
    const unsigned short* __restrict__ A, int lda,
    const unsigned short* __restrict__ W, int ldw,
    const float* __restrict__ bias,
    const unsigned short* __restrict__ resb, int ldr,
    float* __restrict__ outf, unsigned short* __restrict__ outb,
    float* __restrict__ pacc, int ldo,
    int M, int N, int K, int mode)
{
    __shared__ unsigned short As[NSTAGE][128 * 32];   // 8 KB per stage
    __shared__ unsigned short Bs[NSTAGE][128 * 32];

    const int t    = threadIdx.x;
    const int lane = t & 63;
    const int wv   = t >> 6;
    const int wm   = wv >> 1;
    const int wn   = wv & 1;
    const int bm   = blockIdx.y * 128;
    const int bn   = blockIdx.x * 128;
    const int kz   = blockIdx.z;
    const int Kc   = K / gridDim.z;

    const int qd   = lane >> 4;
    const int l16  = lane & 15;

    f32x4 acc[4][4];
    #pragma unroll
    for (int i = 0; i < 4; i++)
        #pragma unroll
        for (int j = 0; j < 4; j++)
            acc[i][j] = (f32x4){0.f, 0.f, 0.f, 0.f};

    // staging: chunk c = wv*2+i covers LDS rows c*16..+15; lane l -> +l*16B
    const int srow = lane >> 2;
    const int sseg = (lane & 3) * 8;
    const int r0   = (wv * 2 + 0) * 16 + srow;
    const int r1   = (wv * 2 + 1) * 16 + srow;
    const size_t gA0 = (size_t)(bm + r0) * lda + sseg;
    const size_t gA1 = (size_t)(bm + r1) * lda + sseg;
    const size_t gB0 = (size_t)(bn + r0) * ldw + sseg;
    const size_t gB1 = (size_t)(bn + r1) * ldw + sseg;
    const int c0 = (wv * 2 + 0) * 512;
    const int c1 = (wv * 2 + 1) * 512;

    const int kbeg  = kz * Kc;
    const int niter = Kc / 32;

    // prologue: tiles 0,1
    async_load16(A + gA0 + kbeg, &As[0][c0]);
    async_load16(W + gB0 + kbeg, &Bs[0][c0]);
    async_load16(A + gA1 + kbeg, &As[0][c1]);
    async_load16(W + gB1 + kbeg, &Bs[0][c1]);
    if (niter > 1) {
        async_load16(A + gA0 + kbeg + 32, &As[1][c0]);
        async_load16(W + gB0 + kbeg + 32, &Bs[1][c0]);
        async_load16(A + gA1 + kbeg + 32, &As[1][c1]);
        async_load16(W + gB1 + kbeg + 32, &Bs[1][c1]);
    }

    int stage = 0;
    for (int it = 0; it < niter; it++) {
        if (it + 1 < niter) __builtin_amdgcn_s_waitcnt(0x0F74);  // vmcnt(4)
        else                __builtin_amdgcn_s_waitcnt(0x0F70);  // vmcnt(0)
        __builtin_amdgcn_s_barrier();   // tile it ready everywhere; stage (it-1)%3 free

        if (it + 2 < niter) {
            const int sn = (stage + 2 >= NSTAGE) ? stage + 2 - NSTAGE : stage + 2;
            const int kn = kbeg + (it + 2) * 32;
            async_load16(A + gA0 + kn, &As[sn][c0]);
            async_load16(W + gB0 + kn, &Bs[sn][c0]);
            async_load16(A + gA1 + kn, &As[sn][c1]);
            async_load16(W + gB1 + kn, &Bs[sn][c1]);
        }

        short8 af[4], bf[4];
        #pragma unroll
        for (int mt = 0; mt < 4; mt++)
            af[mt] = *(const short8*)(&As[stage][(wm * 64 + mt * 16 + l16) * 32 + qd * 8]);
        #pragma unroll
        for (int nt = 0; nt < 4; nt++)
            bf[nt] = *(const short8*)(&Bs[stage][(wn * 64 + nt * 16 + l16) * 32 + qd * 8]);
        #pragma unroll
        for (int mt = 0; mt < 4; mt++)
            #pragma unroll
            for (int nt = 0; nt < 4; nt++)
                acc[mt][nt] = __builtin_amdgcn_mfma_f32_16x16x32_bf16(
                    af[mt], bf[nt], acc[mt][nt], 0, 0, 0);

        stage = (stage == NSTAGE - 1) ? 0 : stage + 1;
    }

    #pragma unroll
    for (int mt = 0; mt < 4; mt++) {
        #pragma unroll
        for (int nt = 0; nt < 4; nt++) {
            int col = bn + wn * 64 + nt * 16 + l16;
            float bv = (kz == 0) ? bias[col] : 0.f;
            #pragma unroll
            for (int r = 0; r < 4; r++) {
                int row = bm + wm * 64 + mt * 16 + qd * 4 + r;
                if (kz != 0) {
                    pacc[(size_t)row * ldo + col] = acc[mt][nt][r];
                    continue;
                }
                float v = acc[mt][nt][r] + bv;
                if (mode == 1) {
                    v += bf2f(resb[(size_t)row * ldr + col]);
                    outf[(size_t)row * ldo + col] = v;
                } else if (mode == 2) {
                    v = 0.5f * v * (1.0f + erff(v * 0.70710678118654752f));
                    outb[(size_t)row * ldo + col] = f2bf(v);
                } else if (mode == 3) {
                    outb[(size_t)row * ldo + col] = f2bf(v);
                } else {
                    outf[(size_t)row * ldo + col] = v;
                }
            }
        }
    }
}

// ---------------- QKV GEMM: standalone NS=4/BK=32 + 8x9 rect (R11-verified 66us) ---
// R12 lesson: BK=64/NS=2 regressed this kernel (vmcnt(8) 2-tile slack was doing
// real work at short K). Keep the deep-pipeline form.
__global__ __launch_bounds__(256) void gemm_qkv(
    const unsigned short* __restrict__ A,
    const unsigned short* __restrict__ W,
    const float* __restrict__ bias,
    unsigned short* __restrict__ outb)
{
    __shared__ unsigned short As[4][128 * 32];
    __shared__ unsigned short Bs[4][128 * 32];

    const int t    = threadIdx.x;
    const int lane = t & 63;
    const int wv   = t >> 6;
    const int wm   = wv >> 1;
    const int wn   = wv & 1;

    // rect 8x9 per XCD over the 18x32 grid (assumes xcd = flat % 8 round-robin)
    const int flat = blockIdx.y * 18 + blockIdx.x;
    const int xcd  = flat & 7;
    const int u    = flat >> 3;
    const int mi   = (xcd >> 1) * 8 + u / 9;
    const int ni   = (xcd & 1) * 9 + u % 9;
    const int bm   = mi * 128;
    const int bn   = ni * 128;

    const int qd   = lane >> 4;
    const int l16  = lane & 15;

    f32x4 acc[4][4];
    #pragma unroll
    for (int i = 0; i < 4; i++)
        #pragma unroll
        for (int j = 0; j < 4; j++)
            acc[i][j] = (f32x4){0.f, 0.f, 0.f, 0.f};

    const int srow = lane >> 2;
    const int sseg = (lane & 3) * 8;
    const int r0   = (wv * 2 + 0) * 16 + srow;
    const int r1   = (wv * 2 + 1) * 16 + srow;
    const size_t gA0 = (size_t)(bm + r0) * D_MODEL + sseg;
    const size_t gA1 = (size_t)(bm + r1) * D_MODEL + sseg;
    const size_t gB0 = (size_t)(bn + r0) * D_MODEL + sseg;
    const size_t gB1 = (size_t)(bn + r1) * D_MODEL + sseg;
    const int c0 = (wv * 2 + 0) * 512;
    const int c1 = (wv * 2 + 1) * 512;

    const int niter = D_MODEL / 32;   // 24

    // prologue: tiles 0,1,2
    async_load16(A + gA0, &As[0][c0]);
    async_load16(W + gB0, &Bs[0][c0]);
    async_load16(A + gA1, &As[0][c1]);
    async_load16(W + gB1, &Bs[0][c1]);
    async_load16(A + gA0 + 32, &As[1][c0]);
    async_load16(W + gB0 + 32, &Bs[1][c0]);
    async_load16(A + gA1 + 32, &As[1][c1]);
    async_load16(W + gB1 + 32, &Bs[1][c1]);
    async_load16(A + gA0 + 64, &As[2][c0]);
    async_load16(W + gB0 + 64, &Bs[2][c0]);
    async_load16(A + gA1 + 64, &As[2][c1]);
    async_load16(W + gB1 + 64, &Bs[2][c1]);

    int stage = 0;
    for (int it = 0; it < niter; it++) {
        if      (it + 2 < niter) __builtin_amdgcn_s_waitcnt(0x0F78);  // vmcnt(8)
        else if (it + 1 < niter) __builtin_amdgcn_s_waitcnt(0x0F74);  // vmcnt(4)
        else                     __builtin_amdgcn_s_waitcnt(0x0F70);  // vmcnt(0)
        __builtin_amdgcn_s_barrier();

        if (it + 3 < niter) {
            int sn = stage + 3;
            if (sn >= 4) sn -= 4;
            const int kn = (it + 3) * 32;
            async_load16(A + gA0 + kn, &As[sn][c0]);
            async_load16(W + gB0 + kn, &Bs[sn][c0]);
            async_load16(A + gA1 + kn, &As[sn][c1]);
            async_load16(W + gB1 + kn, &Bs[sn][c1]);
        }

        short8 af[4], bf[4];
        #pragma unroll
        for (int mt = 0; mt < 4; mt++)
            af[mt] = *(const short8*)(&As[stage][(wm * 64 + mt * 16 + l16) * 32 + qd * 8]);
        #pragma unroll
        for (int nt = 0; nt < 4; nt++)
            bf[nt] = *(const short8*)(&Bs[stage][(wn * 64 + nt * 16 + l16) * 32 + qd * 8]);
        #pragma unroll
        for (int mt = 0; mt < 4; mt++)
            #pragma unroll
            for (int nt = 0; nt < 4; nt++)
                acc[mt][nt] = __builtin_amdgcn_mfma_f32_16x16x32_bf16(
                    af[mt], bf[nt], acc[mt][nt], 0, 0, 0);

        stage = (stage == 3) ? 0 : stage + 1;
    }

    #pragma unroll
    for (int mt = 0; mt < 4; mt++) {
        #pragma unroll
        for (int nt = 0; nt < 4; nt++) {
            int col = bn + wn * 64 + nt * 16 + l16;
            float bv = bias[col];
            #pragma unroll
            for (int r = 0; r < 4; r++) {
                int row = bm + wm * 64 + mt * 16 + qd * 4 + r;
                outb[(size_t)row * QKV_LD + col] = f2bf(acc[mt][nt][r] + bv);
            }
        }
    }
}

// ---------------- FFN1 GEMM: standalone NSTAGE=3/BK=32 + 8x12 rect + gelu ----------
// R11-verified form (FETCH 15.8 MB, 3 blocks/CU). R12 lesson: 64KB-LDS variant cut
// occupancy to 2 blocks/CU and regressed; keep 48 KB.
__global__ __launch_bounds__(256) void gemm_ffn1(
    const unsigned short* __restrict__ A,
    const unsigned short* __restrict__ W,
    const float* __restrict__ bias,
    unsigned short* __restrict__ outb)
{
    __shared__ unsigned short As[NSTAGE][128 * 32];
    __shared__ unsigned short Bs[NSTAGE][128 * 32];

    const int t    = threadIdx.x;
    const int lane = t & 63;
    const int wv   = t >> 6;
    const int wm   = wv >> 1;
    const int wn   = wv & 1;

    // rect 8x12 per XCD over the 24x32 grid (xcd = flat % 8 round-robin)
    const int flat = blockIdx.y * 24 + blockIdx.x;
    const int xcd  = flat & 7;
    const int u    = flat >> 3;
    const int mi   = (xcd >> 1) * 8 + u / 12;
    const int ni   = (xcd & 1) * 12 + u % 12;
    const int bm   = mi * 128;
    const int bn   = ni * 128;

    const int qd   = lane >> 4;
    const int l16  = lane & 15;

    f32x4 acc[4][4];
    #pragma unroll
    for (int i = 0; i < 4; i++)
        #pragma unroll
        for (int j = 0; j < 4; j++)
            acc[i][j] = (f32x4){0.f, 0.f, 0.f, 0.f};

    const int srow = lane >> 2;
    const int sseg = (lane & 3) * 8;
    const int r0   = (wv * 2 + 0) * 16 + srow;
    const int r1   = (wv * 2 + 1) * 16 + srow;
    const size_t gA0 = (size_t)(bm + r0) * D_MODEL + sseg;
    const size_t gA1 = (size_t)(bm + r1) * D_MODEL + sseg;
    const size_t gB0 = (size_t)(bn + r0) * D_MODEL + sseg;
    const size_t gB1 = (size_t)(bn + r1) * D_MODEL + sseg;
    const int c0 = (wv * 2 + 0) * 512;
    const int c1 = (wv * 2 + 1) * 512;

    const int niter = D_MODEL / 32;   // 24

    // prologue: tiles 0,1
    async_load16(A + gA0, &As[0][c0]);
    async_load16(W + gB0, &Bs[0][c0]);
    async_load16(A + gA1, &As[0][c1]);
    async_load16(W + gB1, &Bs[0][c1]);
    async_load16(A + gA0 + 32, &As[1][c0]);
    async_load16(W + gB0 + 32, &Bs[1][c0]);
    async_load16(A + gA1 + 32, &As[1][c1]);
    async_load16(W + gB1 + 32, &Bs[1][c1]);

    int stage = 0;
    for (int it = 0; it < niter; it++) {
        if (it + 1 < niter) __builtin_amdgcn_s_waitcnt(0x0F74);  // vmcnt(4)
        else                __builtin_amdgcn_s_waitcnt(0x0F70);  // vmcnt(0)
        __builtin_amdgcn_s_barrier();

        if (it + 2 < niter) {
            const int sn = (stage + 2 >= NSTAGE) ? stage + 2 - NSTAGE : stage + 2;
            const int kn = (it + 2) * 32;
            async_load16(A + gA0 + kn, &As[sn][c0]);
            async_load16(W + gB0 + kn, &Bs[sn][c0]);
            async_load16(A + gA1 + kn, &As[sn][c1]);
            async_load16(W + gB1 + kn, &Bs[sn][c1]);
        }

        short8 af[4], bf[4];
        #pragma unroll
        for (int mt = 0; mt < 4; mt++)
            af[mt] = *(const short8*)(&As[stage][(wm * 64 + mt * 16 + l16) * 32 + qd * 8]);
        #pragma unroll
        for (int nt = 0; nt < 4; nt++)
            bf[nt] = *(const short8*)(&Bs[stage][(wn * 64 + nt * 16 + l16) * 32 + qd * 8]);
        #pragma unroll
        for (int mt = 0; mt < 4; mt++)
            #pragma unroll
            for (int nt = 0; nt < 4; nt++)
                acc[mt][nt] = __builtin_amdgcn_mfma_f32_16x16x32_bf16(
                    af[mt], bf[nt], acc[mt][nt], 0, 0, 0);

        stage = (stage == NSTAGE - 1) ? 0 : stage + 1;
    }

    #pragma unroll
    for (int mt = 0; mt < 4; mt++) {
        #pragma unroll
        for (int nt = 0; nt < 4; nt++) {
            int col = bn + wn * 64 + nt * 16 + l16;
            float bv = bias[col];
            #pragma unroll
            for (int r = 0; r < 4; r++) {
                int row = bm + wm * 64 + mt * 16 + qd * 4 + r;
                float v = acc[mt][nt][r] + bv;
                v = 0.5f * v * (1.0f + erff(v * 0.70710678118654752f));
                outb[(size_t)row * D_FF + col] = f2bf(v);
            }
        }
    }
}

// ---------------- FFN2 GEMM v2: BK=64, NSTAGE=2, XOR-swizzled LDS (verified R11) ---
__global__ __launch_bounds__(256) void gemm_ffn2(
    const unsigned short* __restrict__ A,     // ff1b [4096,3072]
    const unsigned short* __restrict__ W,     // w2b  [768,3072]
    const float* __restrict__ bias,
    const unsigned short* __restrict__ resb,  // x1b
    float* __restrict__ outf,                 // y0
    float* __restrict__ pacc)                 // p1
{
    __shared__ unsigned short As[2][128 * 64];   // 16 KB per stage
    __shared__ unsigned short Bs[2][128 * 64];

    const int t    = threadIdx.x;
    const int lane = t & 63;
    const int wv   = t >> 6;
    const int wm   = wv >> 1;
    const int wn   = wv & 1;

    const int flat = blockIdx.x;          // 0..383
    const int g    = flat & 7;            // XCD
    const int u    = flat >> 3;           // 0..47
    const int kz   = g >> 2;              // K-half
    const int g2   = g & 3;               // row-stripe group
    const int band = u / 24;              // 2 bands of 4 rows (time-phased)
    const int rr   = (u % 24) / 6;
    const int cc   = u % 6;
    const int bm   = (g2 * 8 + band * 4 + rr) * 128;
    const int bn   = cc * 128;

    const int qd   = lane >> 4;
    const int l16  = lane & 15;

    f32x4 acc[4][4];
    #pragma unroll
    for (int i = 0; i < 4; i++)
        #pragma unroll
        for (int j = 0; j < 4; j++)
            acc[i][j] = (f32x4){0.f, 0.f, 0.f, 0.f};

    const int srow8 = lane >> 3;                    // 0..7 (row & 7)
    const int scol  = ((lane & 7) ^ srow8) * 8;     // swizzled source col (ushorts)
    const size_t gA_base = (size_t)(bm + wv * 32 + srow8) * D_FF + scol;
    const size_t gB_base = (size_t)(bn + wv * 32 + srow8) * D_FF + scol;
    const int ldsb = wv * 4 * 512;                  // element offset of chunk wv*4

    const int kbeg  = kz * (D_FF / 2);    // 0 or 1536
    const int niter = (D_FF / 2) / 64;    // 24

    #pragma unroll
    for (int j = 0; j < 4; j++) {
        async_load16(A + gA_base + (size_t)(j * 8) * D_FF + kbeg, &As[0][ldsb + j * 512]);
        async_load16(W + gB_base + (size_t)(j * 8) * D_FF + kbeg, &Bs[0][ldsb + j * 512]);
    }

    for (int it = 0; it < niter; it++) {
        __builtin_amdgcn_s_waitcnt(0x0F70);  // vmcnt(0): tile it landed
        __builtin_amdgcn_s_barrier();
        const int st = it & 1;

        if (it + 1 < niter) {
            const int kn = kbeg + (it + 1) * 64;
            #pragma unroll
            for (int j = 0; j < 4; j++) {
                async_load16(A + gA_base + (size_t)(j * 8) * D_FF + kn, &As[st ^ 1][ldsb + j * 512]);
                async_load16(W + gB_base + (size_t)(j * 8) * D_FF + kn, &Bs[st ^ 1][ldsb + j * 512]);
            }
        }

        #pragma unroll
        for (int kk = 0; kk < 2; kk++) {
            short8 af[4], bf[4];
            #pragma unroll
            for (int mt = 0; mt < 4; mt++) {
                const int row = wm * 64 + mt * 16 + l16;
                const int slot = (kk * 4 + qd) ^ (row & 7);
                af[mt] = *(const short8*)&As[st][row * 64 + slot * 8];
            }
            #pragma unroll
            for (int nt = 0; nt < 4; nt++) {
                const int row = wn * 64 + nt * 16 + l16;
                const int slot = (kk * 4 + qd) ^ (row & 7);
                bf[nt] = *(const short8*)&Bs[st][row * 64 + slot * 8];
            }
            #pragma unroll
            for (int mt = 0; mt < 4; mt++)
                #pragma unroll
                for (int nt = 0; nt < 4; nt++)
                    acc[mt][nt] = __builtin_amdgcn_mfma_f32_16x16x32_bf16(
                        af[mt], bf[nt], acc[mt][nt], 0, 0, 0);
        }
    }

    #pragma unroll
    for (int mt = 0; mt < 4; mt++) {
        #pragma unroll
        for (int nt = 0; nt < 4; nt++) {
            int col = bn + wn * 64 + nt * 16 + l16;
            #pragma unroll
            for (int r = 0; r < 4; r++) {
                int row = bm + wm * 64 + mt * 16 + qd * 4 + r;
                if (kz != 0) {
                    pacc[(size_t)row * D_MODEL + col] = acc[mt][nt][r];
                } else {
                    float v = acc[mt][nt][r] + bias[col]
                            + bf2f(resb[(size_t)row * D_MODEL + col]);
                    outf[(size_t)row * D_MODEL + col] = v;
                }
            }
        }
    }
}

// ---------------- one-shot V transpose: qkv V-part -> vT[b,h,d,s] ------------------
__global__ __launch_bounds__(256) void vtrans(
    const unsigned short* __restrict__ qkv, unsigned short* __restrict__ vT)
{
    __shared__ unsigned short T[64 * 72];
    const int t   = threadIdx.x;
    const int kt  = blockIdx.x;          // key tile
    const int bh  = blockIdx.y;
    const int h   = bh % N_HEAD;
    const int b   = bh / N_HEAD;
    const int row = t >> 2;              // token within tile
    const int c0  = (t & 3) * 16;        // dim start

    const unsigned short* src =
        qkv + (size_t)(b * SEQ + kt * 64 + row) * QKV_LD + 1536 + h * HEAD_D + c0;
    *(ushort8*)&T[row * 72 + c0]     = *(const ushort8*)src;
    *(ushort8*)&T[row * 72 + c0 + 8] = *(const ushort8*)(src + 8);
    __syncthreads();

    const int d = t >> 2;                // dim row to write
    ushort8 o0, o1;
    #pragma unroll
    for (int j = 0; j < 8; j++) o0[j] = T[(c0 + j) * 72 + d];
    #pragma unroll
    for (int j = 0; j < 8; j++) o1[j] = T[(c0 + 8 + j) * 72 + d];
    unsigned short* dst = vT + ((size_t)bh * HEAD_D + d) * SEQ + kt * 64 + c0;
    *(ushort8*)dst       = o0;
    *(ushort8*)(dst + 8) = o1;
}

// ---------------- MFMA flash attention: S^T form, KVBLK=128 + defer-rescale --------
// Verified R9-R12: 61-62.6 us. ONE new delta this round: T13 defer-rescale guard.
// When no lane's running max grew (mx <= m_st for all lanes), the rescale path is
// alpha==1 exactly -> skipping it is bit-identical. When any lane grew, all lanes
// take the original path (unchanged numerics).
#define ASTR 72
#define VSTR 136

__global__ __launch_bounds__(256) void attn_mfma(
    const unsigned short* __restrict__ qkv, const unsigned short* __restrict__ vT,
    const float* __restrict__ mask, unsigned short* __restrict__ out)
{
    __shared__ __align__(16) unsigned short Ks[128 * ASTR];
    __shared__ __align__(16) unsigned short Vt[64 * VSTR];
    __shared__ float Ms[128];

    const int t    = threadIdx.x;
    const int lane = t & 63;
    const int wv   = t >> 6;
    const int l16  = lane & 15;
    const int quad = lane >> 4;
    const int q0   = blockIdx.x * 64;
    const int bh   = blockIdx.y;
    const int h    = bh % N_HEAD;
    const int b    = bh / N_HEAD;
    const int NT   = SEQ / 128;   // 16

    const unsigned short* qb  = qkv + (size_t)b * SEQ * QKV_LD + h * HEAD_D;
    const unsigned short* kb  = qb + 768;
    const unsigned short* vtb = vT + (size_t)bh * HEAD_D * SEQ;

    // ---- stage Q tile (rows 0..63 of Ks, natural rows), pull Q B-frags ----
    {
        const int qsrow = t >> 2;
        const int qsc0  = (t & 3) * 16;
        const ushort8* src = (const ushort8*)(qb + (size_t)(q0 + qsrow) * QKV_LD + qsc0);
        *(ushort8*)&Ks[qsrow * ASTR + qsc0]     = src[0];
        *(ushort8*)&Ks[qsrow * ASTR + qsc0 + 8] = src[1];
    }
    __syncthreads();
    short8 bq0 = *(const short8*)&Ks[(wv * 16 + l16) * ASTR + quad * 8];
    short8 bq1 = *(const short8*)&Ks[(wv * 16 + l16) * ASTR + 32 + quad * 8];
    __syncthreads();

    // K staging: row = t>>1 (0..127 keys), dim start (t&1)*32 (64B = 4 ushort8)
    const int krow_s = t >> 1;
    const int kc0    = (t & 1) * 32;
    const int ks6    = krow_s & 63;
    const int ksig   = (krow_s & 64) |
                       ((ks6 & 0x23) | ((ks6 & 0x04) << 2) | ((ks6 & 0x18) >> 1));
    // V staging: dim row = t>>2 (0..63), key col start (t&3)*32
    const int vrow_s = t >> 2;
    const int vc0    = (t & 3) * 32;

    f32x4 o[4];
    #pragma unroll
    for (int i = 0; i < 4; i++) o[i] = (f32x4){0.f, 0.f, 0.f, 0.f};
    float m_st = -INFINITY, l_st = 0.f;

    // prefetch tile 0 into registers
    ushort8 rk0, rk1, rk2, rk3, rv0, rv1, rv2, rv3;
    float rm = 1.0f;
    {
        const ushort8* ksrc = (const ushort8*)(kb + (size_t)krow_s * QKV_LD + kc0);
        rk0 = ksrc[0]; rk1 = ksrc[1]; rk2 = ksrc[2]; rk3 = ksrc[3];
        const ushort8* vsrc = (const ushort8*)(vtb + (size_t)vrow_s * SEQ + vc0);
        rv0 = vsrc[0]; rv1 = vsrc[1]; rv2 = vsrc[2]; rv3 = vsrc[3];
        if (t < 128) rm = mask[b * SEQ + t];
    }

    for (int kt = 0; kt < NT; kt++) {
        // ---- store prefetched 128-key tile into LDS ----
        *(ushort8*)&Ks[ksig * ASTR + kc0]      = rk0;
        *(ushort8*)&Ks[ksig * ASTR + kc0 + 8]  = rk1;
        *(ushort8*)&Ks[ksig * ASTR + kc0 + 16] = rk2;
        *(ushort8*)&Ks[ksig * ASTR + kc0 + 24] = rk3;
        *(ushort8*)&Vt[vrow_s * VSTR + vc0]      = rv0;
        *(ushort8*)&Vt[vrow_s * VSTR + vc0 + 8]  = rv1;
        *(ushort8*)&Vt[vrow_s * VSTR + vc0 + 16] = rv2;
        *(ushort8*)&Vt[vrow_s * VSTR + vc0 + 24] = rv3;
        if (t < 128) Ms[t] = -10000.0f * (1.0f - rm);
        __syncthreads();

        // ---- prefetch next tile (latency hidden under compute) ----
        if (kt + 1 < NT) {
            const int kn = (kt + 1) * 128;
            const ushort8* ksrc = (const ushort8*)(kb + (size_t)(kn + krow_s) * QKV_LD + kc0);
            rk0 = ksrc[0]; rk1 = ksrc[1]; rk2 = ksrc[2]; rk3 = ksrc[3];
            const ushort8* vsrc = (const ushort8*)(vtb + (size_t)vrow_s * SEQ + kn + vc0);
            rv0 = vsrc[0]; rv1 = vsrc[1]; rv2 = vsrc[2]; rv3 = vsrc[3];
            if (t < 128) rm = mask[b * SEQ + kn + t];
        }

        // ---- S^T = K·Q^T over 8 slot-blocks, fused with mask+max ----
        float p[8][4];
        float mx = -3.0e38f;
        #pragma unroll
        for (int bi = 0; bi < 8; bi++) {
            const int krow = (bi * 16 + l16) * ASTR;
            short8 k0 = *(const short8*)&Ks[krow + quad * 8];
            short8 k1 = *(const short8*)&Ks[krow + 32 + quad * 8];
            f32x4 z = (f32x4){0.f, 0.f, 0.f, 0.f};
            z = __builtin_amdgcn_mfma_f32_16x16x32_bf16(k0, bq0, z, 0, 0, 0);
            z = __builtin_amdgcn_mfma_f32_16x16x32_bf16(k1, bq1, z, 0, 0, 0);
            const float4 m4 = *(const float4*)
                &Ms[(bi >> 2) * 64 + ((bi >> 1) & 1) * 32 + quad * 8 + (bi & 1) * 4];
            #pragma unroll
            for (int r = 0; r < 4; r++) {
                float s = fmaf(z[r], 0.125f, ((const float*)&m4)[r]);
                p[bi][r] = s;
                mx = fmaxf(mx, s);
            }
        }
        mx = fmaxf(mx, __shfl_xor(mx, 16, 64));
        mx = fmaxf(mx, __shfl_xor(mx, 32, 64));
        // T13 defer-rescale: skip only when alpha == 1 for every lane (bit-identical)
        if (__any(mx > m_st)) {
            float m_new = fmaxf(m_st, mx);
            float alpha = __expf(m_st - m_new);
            m_st = m_new;
            l_st *= alpha;
            float ar[4];
            #pragma unroll
            for (int r = 0; r < 4; r++) ar[r] = __shfl(alpha, quad * 4 + r, 64);
            #pragma unroll
            for (int nt = 0; nt < 4; nt++)
                #pragma unroll
                for (int r = 0; r < 4; r++)
                    o[nt][r] *= ar[r];
        }
        float ls = 0.f;
        #pragma unroll
        for (int bi = 0; bi < 8; bi++) {
            #pragma unroll
            for (int r = 0; r < 4; r++) {
                p[bi][r] = __expf(p[bi][r] - m_st);
                ls += p[bi][r];
            }
        }
        ls += __shfl_xor(ls, 16, 64);
        ls += __shfl_xor(ls, 32, 64);
        l_st += ls;

        // ---- pack P to bf16 A-frags: window w covers keys w*32..+31 ----
        short8 pf[4];
        #pragma unroll
        for (int w = 0; w < 4; w++) {
            #pragma unroll
            for (int bsel = 0; bsel < 2; bsel++) {
                #pragma unroll
                for (int r = 0; r < 4; r++)
                    pf[w][bsel * 4 + r] = (short)f2bf(p[w * 2 + bsel][r]);
            }
        }

        // ---- PV: O += P · V over 4 key-windows ----
        #pragma unroll
        for (int nt = 0; nt < 4; nt++) {
            const int vrow = (nt * 16 + l16) * VSTR;
            #pragma unroll
            for (int w = 0; w < 4; w++) {
                short8 vv = *(const short8*)&Vt[vrow + w * 32 + quad * 8];
                o[nt] = __builtin_amdgcn_mfma_f32_16x16x32_bf16(pf[w], vv, o[nt], 0, 0, 0);
            }
        }
        __syncthreads();
    }

    float inv = 1.0f / l_st;
    float ir[4];
    #pragma unroll
    for (int r = 0; r < 4; r++) ir[r] = __shfl(inv, quad * 4 + r, 64);
    #pragma unroll
    for (int nt = 0; nt < 4; nt++) {
        #pragma unroll
        for (int r = 0; r < 4; r++) {
            int qi = q0 + wv * 16 + quad * 4 + r;
            out[(size_t)(b * SEQ + qi) * D_MODEL + h * HEAD_D + nt * 16 + l16] =
                f2bf(o[nt][r] * ir[r]);
        }
    }
}

// ---------------- LayerNorm over 768; optional second f32 input (split-K partial) --
__global__ __launch_bounds__(256) void ln_kernel(
    const float* __restrict__ in, const float* __restrict__ in2,
    const float* __restrict__ g, const float* __restrict__ be,
    float* __restrict__ outf, unsigned short* __restrict__ outb)
{
    const int row = blockIdx.x;
    const int t   = threadIdx.x;
    const float* rp  = in  + (size_t)row * D_MODEL;
    const float* rp2 = in2 ? in2 + (size_t)row * D_MODEL : nullptr;

    float vals[3];
    float s = 0.f, s2 = 0.f;
    #pragma unroll
    for (int i = 0; i < 3; i++) {
        float x = rp[t + i * 256];
        if (rp2) x += rp2[t + i * 256];
        vals[i] = x;
        s += x; s2 += x * x;
    }
    #pragma unroll
    for (int off = 32; off >= 1; off >>= 1) {
        s  += __shfl_xor(s,  off, 64);
        s2 += __shfl_xor(s2, off, 64);
    }
    __shared__ float rs[4], rs2[4];
    __shared__ float mu_s, rstd_s;
    const int wave = t >> 6, lane = t & 63;
    if (lane == 0) { rs[wave] = s; rs2[wave] = s2; }
    __syncthreads();
    if (t == 0) {
        float S1 = rs[0] + rs[1] + rs[2] + rs[3];
        float S2 = rs2[0] + rs2[1] + rs2[2] + rs2[3];
        float mu  = S1 * (1.0f / D_MODEL);
        float var = S2 * (1.0f / D_MODEL) - mu * mu;
        mu_s = mu;
        rstd_s = rsqrtf(var + 1e-12f);
    }
    __syncthreads();
    const float mu = mu_s, rstd = rstd_s;
    #pragma unroll
    for (int i = 0; i < 3; i++) {
        int c = t + i * 256;
        float o = g[c] * (vals[i] - mu) * rstd + be[c];
        if (outf) outf[(size_t)row * D_MODEL + c] = o;
        if (outb) outb[(size_t)row * D_MODEL + c] = f2bf(o);
    }
}

extern "C" void kernel_launch(void* const* d_in, const int* in_sizes, int n_in,
                              void* d_out, int out_size, void* d_ws, size_t ws_size,
                              hipStream_t stream)
{
    const float* x    = (const float*)d_in[0];
    const float* mask = (const float*)d_in[1];
    const float* Wq   = (const float*)d_in[2];
    const float* bq   = (const float*)d_in[3];
    const float* Wk   = (const float*)d_in[4];
    const float* bk   = (const float*)d_in[5];
    const float* Wv   = (const float*)d_in[6];
    const float* bv   = (const float*)d_in[7];
    const float* Wp   = (const float*)d_in[8];
    const float* bp   = (const float*)d_in[9];
    const float* g1   = (const float*)d_in[10];
    const float* be1  = (const float*)d_in[11];
    const float* W1   = (const float*)d_in[12];
    const float* bf1  = (const float*)d_in[13];
    const float* W2   = (const float*)d_in[14];
    const float* bf2  = (const float*)d_in[15];
    const float* g2   = (const float*)d_in[16];
    const float* be2  = (const float*)d_in[17];

    const int M = BATCH * SEQ;   // 4096

    // ---- workspace layout (bytes), ~83.4 MB total ----
    char* ws = (char*)d_ws;
    unsigned short* qkvb  = (unsigned short*)(ws + 0);         // [4096,2304] bf16
    unsigned short* ff1b  = (unsigned short*)(ws + 0);         // [4096,3072] bf16 (qkvb dead)
    unsigned short* xb    = (unsigned short*)(ws + 25165824);  // [4096,768] bf16 (live thru proj)
    unsigned short* hb    = (unsigned short*)(ws + 31457280);  // [4096,768] bf16
    unsigned short* x1b   = (unsigned short*)(ws + 31457280);  // alias (hb dead after proj)
    float*          y0    = (float*)(ws + 37748736);           // [4096,768] f32
    unsigned short* wqkvb = (unsigned short*)(ws + 50331648);  // [2304,768]
    unsigned short* wpb   = (unsigned short*)(ws + 53870592);  // [768,768]
    unsigned short* w1b   = (unsigned short*)(ws + 55050240);  // [3072,768]
    unsigned short* w2b   = (unsigned short*)(ws + 59768832);  // [768,3072]
    float*          bqkv  = (float*)(ws + 64487424);           // [2304]
    float*          p1    = (float*)(ws + 64496640);           // [4096,768] f32 split-K partial
    unsigned short* vTb   = (unsigned short*)(ws + 77079552);  // [24,64,2048] bf16 (6.3MB)

    dim3 blk(256);

    conv_fused<<<dim3(9985), blk, 0, stream>>>(
        x, Wq, Wk, Wv, Wp, W1, W2, bq, bk, bv,
        xb, wqkvb, wpb, w1b, w2b, bqkv);

    // fused QKV GEMM -> bf16 (R11-verified NS=4/BK=32 rect kernel)
    gemm_qkv<<<dim3(QKV_LD / 128, M / 128), blk, 0, stream>>>(xb, wqkvb, bqkv, qkvb);

    // one-shot V transpose
    vtrans<<<dim3(SEQ / 64, BATCH * N_HEAD), blk, 0, stream>>>(qkvb, vTb);

    // flash attention -> hb (bf16): KVBLK=128 + defer-rescale (only new delta)
    attn_mfma<<<dim3(SEQ / 64, BATCH * N_HEAD), blk, 0, stream>>>(qkvb, vTb, mask, hb);

    // proj + residual, split-K x2: y0 (z=0: bias + xb) + p1 (z=1 raw)
    gemm_bf16<<<dim3(D_MODEL / 128, M / 128, 2), blk, 0, stream>>>(
        hb, D_MODEL, wpb, D_MODEL, bp, xb, D_MODEL,
        y0, nullptr, p1, D_MODEL, M, D_MODEL, D_MODEL, 1);

    // LN1 over (y0 + p1) -> x1b (bf16)
    ln_kernel<<<dim3(M), blk, 0, stream>>>(y0, p1, g1, be1, nullptr, x1b);

    // FFN1 + gelu -> ff1b (R11-verified NSTAGE=3 rect kernel)
    gemm_ffn1<<<dim3(D_FF / 128, M / 128), blk, 0, stream>>>(x1b, w1b, bf1, ff1b);

    // FFN2 + residual, split-K x2 (v2 verified R11)
    gemm_ffn2<<<dim3(384), blk, 0, stream>>>(ff1b, w2b, bf2, x1b, y0, p1);

    // LN2 over (y0 + p1) -> out (f32)
    ln_kernel<<<dim3(M), blk, 0, stream>>>(y0, p1, g2, be2, (float*)d_out, nullptr);
}